// Round 5
// baseline (4514.013 us; speedup 1.0000x reference)
//
#include <hip/hip_runtime.h>
#include <cstdint>
#include <cstddef>

#define N_NODES 50000
#define NE      1600000
#define FIN     128
#define HDIM    256
#define EDIM    64
#define NGR     64
#define NCLS    10

// ---------- bf16 helpers (raw ushort storage, fp32 compute) ----------
__device__ __forceinline__ float b2f(unsigned short u) {
  union { uint32_t i; float f; } v; v.i = ((uint32_t)u) << 16; return v.f;
}
__device__ __forceinline__ unsigned short f2b(float f) {
  union { float f; uint32_t i; } v; v.f = f;
  uint32_t r = v.i + 0x7fff + ((v.i >> 16) & 1);   // round-to-nearest-even
  return (unsigned short)(r >> 16);
}

// ============================================================
// CSR build (by dst)
// ============================================================
__global__ void k_count(const int* __restrict__ dst, int* __restrict__ cnt) {
  int e = blockIdx.x * 256 + threadIdx.x;
  if (e < NE) atomicAdd(&cnt[dst[e]], 1);
}

__global__ __launch_bounds__(1024) void k_scan(int* __restrict__ cnt, int* __restrict__ rp) {
  __shared__ int s[1024];
  __shared__ int base_s;
  int t = threadIdx.x;
  if (t == 0) { base_s = 0; rp[0] = 0; }
  __syncthreads();
  for (int c0 = 0; c0 < N_NODES; c0 += 1024) {
    int i = c0 + t;
    int v = (i < N_NODES) ? cnt[i] : 0;
    s[t] = v;
    __syncthreads();
    for (int off = 1; off < 1024; off <<= 1) {
      int add = (t >= off) ? s[t - off] : 0;
      __syncthreads();
      s[t] += add;
      __syncthreads();
    }
    int incl = s[t];
    int base = base_s;
    if (i < N_NODES) {
      int excl = base + incl - v;
      cnt[i] = excl;     // becomes scatter cursor
      rp[i]  = excl;
      if (i == N_NODES - 1) rp[N_NODES] = base + incl;
    }
    __syncthreads();
    if (t == 1023) base_s = base + incl;
    __syncthreads();
  }
}

__global__ void k_scatter(const int* __restrict__ src, const int* __restrict__ dst,
                          int* __restrict__ cur, int* __restrict__ ssrc,
                          int* __restrict__ epos) {
  int e = blockIdx.x * 256 + threadIdx.x;
  if (e < NE) {
    int d = dst[e];
    int pos = atomicAdd(&cur[d], 1);
    ssrc[pos] = src[e];
    epos[e] = pos;
  }
}

// ============================================================
// precompute folded conv2 matrices:
//  M    = w3b @ g2_we        (64x256)   [w3b = w3 rows 64..127]
//  W_a  = w3a @ g2_we        (64x256)   [w3a = w3 rows 0..63]
// ============================================================
__global__ __launch_bounds__(256) void k_pre1(const float* __restrict__ w3,
    const float* __restrict__ g2we, float* __restrict__ M, float* __restrict__ Wa) {
  int idx = blockIdx.x * 256 + threadIdx.x;          // 32768
  int which = idx >> 14;                              // 0: M (w3b), 1: Wa (w3a)
  int k = (idx >> 8) & 63, d = idx & 255;
  const float* wrow = w3 + (size_t)(which ? k : (64 + k)) * 64;
  float a = 0.f;
#pragma unroll 8
  for (int j = 0; j < 64; j++) a = fmaf(wrow[j], g2we[j * 256 + d], a);
  (which ? Wa : M)[k * 256 + d] = a;
}

// ============================================================
//  T_hs = w2[0:256]   @ M    (256x256)
//  T_hd = w2[256:512] @ M    (256x256)
//  bias2 = b2 @ M + b3 @ g2_we   (256)
// ============================================================
__global__ __launch_bounds__(256) void k_pre2(const float* __restrict__ w2,
    const float* __restrict__ b2, const float* __restrict__ b3,
    const float* __restrict__ M, const float* __restrict__ g2we,
    float* __restrict__ Ths, float* __restrict__ Thd, float* __restrict__ bias2) {
  int idx = blockIdx.x * 256 + threadIdx.x;          // grid 513 -> 131328
  if (idx < 65536) {
    int k = idx >> 8, d = idx & 255;
    float a = 0.f;
#pragma unroll 8
    for (int j = 0; j < 64; j++) a = fmaf(w2[(size_t)k * 64 + j], M[j * 256 + d], a);
    Ths[(size_t)k * 256 + d] = a;
  } else if (idx < 131072) {
    int k = (idx - 65536) >> 8, d = idx & 255;
    float a = 0.f;
#pragma unroll 8
    for (int j = 0; j < 64; j++) a = fmaf(w2[(size_t)(256 + k) * 64 + j], M[j * 256 + d], a);
    Thd[(size_t)k * 256 + d] = a;
  } else if (idx < 131328) {
    int d = idx - 131072;
    float a = 0.f;
#pragma unroll 8
    for (int j = 0; j < 64; j++) {
      a = fmaf(b2[j], M[j * 256 + d], a);
      a = fmaf(b3[j], g2we[j * 256 + d], a);
    }
    bias2[d] = a;
  }
}

// ============================================================
// perm_invariant_net per-edge; output quantized uint8 with per-edge scale
// ============================================================
__global__ __launch_bounds__(256) void k_perm(const float* __restrict__ raw,
    const float* __restrict__ pw1, const float* __restrict__ pb1,
    const float* __restrict__ pw2, const float* __restrict__ pb2,
    const float* __restrict__ pws, const float* __restrict__ pbs,
    uint8_t* __restrict__ Q, float* __restrict__ SC) {
  int e = blockIdx.x * 256 + threadIdx.x;   // NE % 256 == 0
  const float4* rp4 = reinterpret_cast<const float4*>(raw + (size_t)e * 8);
  float4 v0 = rp4[0], v1 = rp4[1];
  float x0 = v0.x, x1 = v0.y, x2 = v0.z, x3 = v0.w;
  float x4 = v1.x, x5 = v1.y, x6 = v1.z, x7 = v1.w;
#define CE(a,b) { float lo_ = fminf(a,b), hi_ = fmaxf(a,b); a = lo_; b = hi_; }
  CE(x0,x1) CE(x2,x3) CE(x4,x5) CE(x6,x7)
  CE(x0,x2) CE(x1,x3) CE(x4,x6) CE(x5,x7)
  CE(x1,x2) CE(x5,x6) CE(x0,x4) CE(x3,x7)
  CE(x1,x5) CE(x2,x6)
  CE(x1,x4) CE(x3,x6)
  CE(x2,x4) CE(x3,x5)
  CE(x3,x4)
#undef CE
  float xs[8] = {x0,x1,x2,x3,x4,x5,x6,x7};
  float sum = x0+x1+x2+x3+x4+x5+x6+x7;
  float mean = sum * 0.125f;
  float var = 0.f;
#pragma unroll
  for (int i = 0; i < 8; i++) { float d = xs[i] - mean; var = fmaf(d, d, var); }
  float sd  = sqrtf(var * (1.f / 7.f));   // ddof=1
  float rng = x7 - x0;
  float mx  = x7;

  float f[64];
#pragma unroll
  for (int o = 0; o < 64; o++) f[o] = pb2[o];
#pragma unroll 2
  for (int j = 0; j < 256; j++) {
    float h = pb1[j];
#pragma unroll
    for (int i = 0; i < 8; i++) h = fmaf(xs[i], pw1[i * 256 + j], h);
    h = fmaxf(h, 0.f);
#pragma unroll
    for (int o = 0; o < 64; o++) f[o] = fmaf(h, pw2[j * 64 + o], f[o]);
  }
  float g[64];
#pragma unroll
  for (int o = 0; o < 64; o++)
    g[o] = pbs[o] + rng * pws[64 * 64 + o] + sd * pws[65 * 64 + o] + mx * pws[66 * 64 + o];
#pragma unroll
  for (int k = 0; k < 64; k++) {
    float fk = f[k];
#pragma unroll
    for (int o = 0; o < 64; o++) g[o] = fmaf(fk, pws[k * 64 + o], g[o]);
  }
  // relu + row max
  float mrow = 0.f;
#pragma unroll
  for (int o = 0; o < 64; o++) { g[o] = fmaxf(g[o], 0.f); mrow = fmaxf(mrow, g[o]); }
  float inv = (mrow > 0.f) ? (255.f / mrow) : 0.f;
  SC[e] = mrow * (1.f / 255.f);
  uint32_t pk[16];
#pragma unroll
  for (int w = 0; w < 16; w++) {
    uint32_t q0 = (uint32_t)(g[4*w+0] * inv + 0.5f);
    uint32_t q1 = (uint32_t)(g[4*w+1] * inv + 0.5f);
    uint32_t q2 = (uint32_t)(g[4*w+2] * inv + 0.5f);
    uint32_t q3 = (uint32_t)(g[4*w+3] * inv + 0.5f);
    pk[w] = q0 | (q1 << 8) | (q2 << 16) | (q3 << 24);
  }
  uint4* qp = reinterpret_cast<uint4*>(Q + (size_t)e * 64);
#pragma unroll
  for (int w = 0; w < 4; w++) {
    uint4 v; v.x = pk[4*w]; v.y = pk[4*w+1]; v.z = pk[4*w+2]; v.w = pk[4*w+3];
    qp[w] = v;
  }
}

// ============================================================
// conv1 node GEMM: out_bf16[M][256] = x_f32 @ W (+bias), K=128
// ============================================================
template<bool BIAS>
__global__ __launch_bounds__(256) void k_gemm_x(const float* __restrict__ A,
    const float* __restrict__ W, const float* __restrict__ bias,
    unsigned short* __restrict__ out, int Mrows) {
  __shared__ float As[32][68];
  __shared__ float Bs[32][64];
  int t = threadIdx.x;
  int m0 = blockIdx.x * 64, n0 = blockIdx.y * 64;
  int tm = t & 15, tn = t >> 4;
  float acc[4][4] = {};
  for (int k0 = 0; k0 < FIN; k0 += 32) {
    {
      int e = t >> 2, kk = (t & 3) * 8;
      int gm = m0 + e;
      float va[8];
      if (gm < Mrows) {
        const float* ap = A + (size_t)gm * FIN + k0 + kk;
        float4 a0 = *reinterpret_cast<const float4*>(ap);
        float4 a1 = *reinterpret_cast<const float4*>(ap + 4);
        va[0]=a0.x; va[1]=a0.y; va[2]=a0.z; va[3]=a0.w;
        va[4]=a1.x; va[5]=a1.y; va[6]=a1.z; va[7]=a1.w;
      } else {
#pragma unroll
        for (int q = 0; q < 8; q++) va[q] = 0.f;
      }
#pragma unroll
      for (int q = 0; q < 8; q++) As[kk + q][e] = va[q];
    }
    {
      int r = t >> 3, c = (t & 7) * 8;
      const float* wp = W + (size_t)(k0 + r) * 256 + n0 + c;
      *reinterpret_cast<float4*>(&Bs[r][c])     = *reinterpret_cast<const float4*>(wp);
      *reinterpret_cast<float4*>(&Bs[r][c + 4]) = *reinterpret_cast<const float4*>(wp + 4);
    }
    __syncthreads();
#pragma unroll
    for (int k = 0; k < 32; k++) {
      float4 a4 = *reinterpret_cast<const float4*>(&As[k][tm * 4]);
      float4 b4 = *reinterpret_cast<const float4*>(&Bs[k][tn * 4]);
      float av[4] = {a4.x, a4.y, a4.z, a4.w};
      float bv[4] = {b4.x, b4.y, b4.z, b4.w};
#pragma unroll
      for (int i = 0; i < 4; i++)
#pragma unroll
        for (int j = 0; j < 4; j++)
          acc[i][j] = fmaf(av[i], bv[j], acc[i][j]);
    }
    __syncthreads();
  }
  float bv4[4] = {0.f, 0.f, 0.f, 0.f};
  if (BIAS) {
#pragma unroll
    for (int j = 0; j < 4; j++) bv4[j] = bias[n0 + tn * 4 + j];
  }
#pragma unroll
  for (int i = 0; i < 4; i++) {
    int gm = m0 + tm * 4 + i;
    if (gm < Mrows) {
      ushort4 o;
      o.x = f2b(acc[i][0] + bv4[0]); o.y = f2b(acc[i][1] + bv4[1]);
      o.z = f2b(acc[i][2] + bv4[2]); o.w = f2b(acc[i][3] + bv4[3]);
      *reinterpret_cast<ushort4*>(out + (size_t)gm * 256 + n0 + tn * 4) = o;
    }
  }
}

// ============================================================
// conv2 node GEMMs from bf16 H:
//   out = relu(h) @ W1  [+ h @ W2]  [+ bias]    (K=256 per pass)
// ============================================================
template<bool W2P, bool BIAS>
__global__ __launch_bounds__(256) void k_gemm_h(const unsigned short* __restrict__ H,
    const float* __restrict__ W1, const float* __restrict__ W2,
    const float* __restrict__ bias, unsigned short* __restrict__ out, int Mrows) {
  __shared__ float As[32][68];
  __shared__ float Bs[32][64];
  int t = threadIdx.x;
  int m0 = blockIdx.x * 64, n0 = blockIdx.y * 64;
  int tm = t & 15, tn = t >> 4;
  float acc[4][4] = {};
  const int passes = W2P ? 2 : 1;
  for (int ps = 0; ps < passes; ps++) {
    const float* W = ps ? W2 : W1;
    for (int k0 = 0; k0 < HDIM; k0 += 32) {
      {
        int e = t >> 2, kk = (t & 3) * 8;
        int gm = m0 + e;
        float va[8];
        if (gm < Mrows) {
          uint4 hv = *reinterpret_cast<const uint4*>(H + (size_t)gm * 256 + k0 + kk);
          uint32_t wd[4] = {hv.x, hv.y, hv.z, hv.w};
#pragma unroll
          for (int q = 0; q < 4; q++) {
            va[2*q]   = b2f((unsigned short)(wd[q] & 0xffff));
            va[2*q+1] = b2f((unsigned short)(wd[q] >> 16));
          }
        } else {
#pragma unroll
          for (int q = 0; q < 8; q++) va[q] = 0.f;
        }
#pragma unroll
        for (int q = 0; q < 8; q++) {
          float v = va[q];
          if (ps == 0) v = fmaxf(v, 0.f);   // relu pass
          As[kk + q][e] = v;
        }
      }
      {
        int r = t >> 3, c = (t & 7) * 8;
        const float* wp = W + (size_t)(k0 + r) * 256 + n0 + c;
        *reinterpret_cast<float4*>(&Bs[r][c])     = *reinterpret_cast<const float4*>(wp);
        *reinterpret_cast<float4*>(&Bs[r][c + 4]) = *reinterpret_cast<const float4*>(wp + 4);
      }
      __syncthreads();
#pragma unroll
      for (int k = 0; k < 32; k++) {
        float4 a4 = *reinterpret_cast<const float4*>(&As[k][tm * 4]);
        float4 b4 = *reinterpret_cast<const float4*>(&Bs[k][tn * 4]);
        float av[4] = {a4.x, a4.y, a4.z, a4.w};
        float bv[4] = {b4.x, b4.y, b4.z, b4.w};
#pragma unroll
        for (int i = 0; i < 4; i++)
#pragma unroll
          for (int j = 0; j < 4; j++)
            acc[i][j] = fmaf(av[i], bv[j], acc[i][j]);
      }
      __syncthreads();
    }
  }
  float bv4[4] = {0.f, 0.f, 0.f, 0.f};
  if (BIAS) {
#pragma unroll
    for (int j = 0; j < 4; j++) bv4[j] = bias[n0 + tn * 4 + j];
  }
#pragma unroll
  for (int i = 0; i < 4; i++) {
    int gm = m0 + tm * 4 + i;
    if (gm < Mrows) {
      ushort4 o;
      o.x = f2b(acc[i][0] + bv4[0]); o.y = f2b(acc[i][1] + bv4[1]);
      o.z = f2b(acc[i][2] + bv4[2]); o.w = f2b(acc[i][3] + bv4[3]);
      *reinterpret_cast<ushort4*>(out + (size_t)gm * 256 + n0 + tn * 4) = o;
    }
  }
}

// ============================================================
// attention logits per edge tile (64 edges):
//   s = xl[src] + xr[dst] + deq(ea) @ we [+ ebias]
//   logit = leaky_relu(s, 0.2) . att; write to CSR slot epos[e]
// ============================================================
template<bool EBIAS>
__global__ __launch_bounds__(256) void k_elogit(
    const uint8_t* __restrict__ Q, const float* __restrict__ SC,
    const int* __restrict__ src, const int* __restrict__ dst,
    const int* __restrict__ epos,
    const unsigned short* __restrict__ xl, const unsigned short* __restrict__ xr,
    const float* __restrict__ we, const float* __restrict__ att,
    const float* __restrict__ ebias, float* __restrict__ lg) {
  __shared__ float ea_t[64][68];     // [k][edge]
  __shared__ float we_s[32][256];
  __shared__ float att_s[256];
  __shared__ float eb_s[256];
  __shared__ int   s_src[64], s_dst[64], s_pos[64];
  __shared__ float red[64][33];
  int t = threadIdx.x;
  int e0 = blockIdx.x * 64;                 // NE % 64 == 0
  if (t < 64) { s_src[t] = src[e0 + t]; s_dst[t] = dst[e0 + t]; s_pos[t] = epos[e0 + t]; }
  att_s[t] = att[t];
  if (EBIAS) eb_s[t] = ebias[t];
  { // stage + dequant ea (all 64 k)
    int e = t >> 2, kk = (t & 3) * 16;
    uint4 qv = *reinterpret_cast<const uint4*>(Q + (size_t)(e0 + e) * 64 + kk);
    float sc = SC[e0 + e];
    uint32_t wd[4] = {qv.x, qv.y, qv.z, qv.w};
#pragma unroll
    for (int q = 0; q < 4; q++) {
      uint32_t u = wd[q];
      ea_t[kk + q*4 + 0][e] = (float)( u         & 0xff) * sc;
      ea_t[kk + q*4 + 1][e] = (float)((u >> 8 )  & 0xff) * sc;
      ea_t[kk + q*4 + 2][e] = (float)((u >> 16)  & 0xff) * sc;
      ea_t[kk + q*4 + 3][e] = (float)( u >> 24         ) * sc;
    }
  }
  int td = t & 31, te = t >> 5;
  float acc[2][4][2][4] = {};
  for (int kh = 0; kh < 2; kh++) {
    { // stage we rows kh*32 .. +31
      int r = t >> 3, c = (t & 7) * 32;
      const float* p = we + (size_t)(kh * 32 + r) * 256 + c;
#pragma unroll
      for (int q = 0; q < 8; q++)
        *reinterpret_cast<float4*>(&we_s[r][c + q * 4]) =
            *reinterpret_cast<const float4*>(p + q * 4);
    }
    __syncthreads();
#pragma unroll
    for (int k = 0; k < 32; k++) {
      int kg = kh * 32 + k;
      float4 a0 = *reinterpret_cast<const float4*>(&ea_t[kg][te * 4]);
      float4 a1 = *reinterpret_cast<const float4*>(&ea_t[kg][32 + te * 4]);
      float4 b0 = *reinterpret_cast<const float4*>(&we_s[k][td * 4]);
      float4 b1 = *reinterpret_cast<const float4*>(&we_s[k][128 + td * 4]);
      float av[2][4] = {{a0.x,a0.y,a0.z,a0.w},{a1.x,a1.y,a1.z,a1.w}};
      float bv[2][4] = {{b0.x,b0.y,b0.z,b0.w},{b1.x,b1.y,b1.z,b1.w}};
#pragma unroll
      for (int g = 0; g < 2; g++)
#pragma unroll
        for (int i = 0; i < 4; i++)
#pragma unroll
          for (int hh = 0; hh < 2; hh++)
#pragma unroll
            for (int j = 0; j < 4; j++)
              acc[g][i][hh][j] = fmaf(av[g][i], bv[hh][j], acc[g][i][hh][j]);
    }
    __syncthreads();
  }
  // epilogue
#pragma unroll
  for (int g = 0; g < 2; g++)
#pragma unroll
    for (int i = 0; i < 4; i++) {
      int el = g * 32 + te * 4 + i;
      const unsigned short* xlp = xl + (size_t)s_src[el] * 256;
      const unsigned short* xrp = xr + (size_t)s_dst[el] * 256;
      float p = 0.f;
#pragma unroll
      for (int hh = 0; hh < 2; hh++) {
        int dbase = hh * 128 + td * 4;
        ushort4 xa = *reinterpret_cast<const ushort4*>(xlp + dbase);
        ushort4 xb = *reinterpret_cast<const ushort4*>(xrp + dbase);
        float xav[4] = {b2f(xa.x), b2f(xa.y), b2f(xa.z), b2f(xa.w)};
        float xbv[4] = {b2f(xb.x), b2f(xb.y), b2f(xb.z), b2f(xb.w)};
#pragma unroll
        for (int j = 0; j < 4; j++) {
          float sv = acc[g][i][hh][j] + xav[j] + xbv[j];
          if (EBIAS) sv += eb_s[dbase + j];
          sv = (sv > 0.f) ? sv : 0.2f * sv;
          p = fmaf(sv, att_s[dbase + j], p);
        }
      }
      red[el][td] = p;
    }
  __syncthreads();
  if (t < 64) {
    float s = 0.f;
#pragma unroll
    for (int j = 0; j < 32; j++) s += red[t][j];
    lg[s_pos[t]] = s;    // scattered into CSR order
  }
}

// ============================================================
// softmax-aggregation per dst node (CSR, sequential reads)
// ============================================================
template<bool POOL>
__global__ __launch_bounds__(256) void k_agg(const int* __restrict__ rp,
    const int* __restrict__ ssrc, const float* __restrict__ lg,
    const unsigned short* __restrict__ xl, const float* __restrict__ bo,
    const int* __restrict__ batch,
    unsigned short* __restrict__ out_b, float* __restrict__ out_pool) {
  int n = blockIdx.x, t = threadIdx.x;
  int beg = rp[n], deg = rp[n + 1] - beg;
  __shared__ float ws_[256];
  __shared__ int   ss_[256];
  __shared__ float rbuf[256];
  float lm = -3.4e38f;
  for (int i = t; i < deg; i += 256) lm = fmaxf(lm, lg[beg + i]);
  rbuf[t] = lm; __syncthreads();
  for (int s = 128; s > 0; s >>= 1) { if (t < s) rbuf[t] = fmaxf(rbuf[t], rbuf[t + s]); __syncthreads(); }
  float m = rbuf[0];
  __syncthreads();
  float acc = 0.f, dpart = 0.f;
  for (int c0 = 0; c0 < deg; c0 += 256) {
    int i = c0 + t;
    float w = 0.f; int sidx = 0;
    if (i < deg) { w = expf(lg[beg + i] - m); sidx = ssrc[beg + i]; dpart += w; }
    ws_[t] = w; ss_[t] = sidx;
    __syncthreads();
    int lim = min(256, deg - c0);
    for (int j = 0; j < lim; j++)
      acc = fmaf(ws_[j], b2f(xl[(size_t)ss_[j] * 256 + t]), acc);
    __syncthreads();
  }
  rbuf[t] = dpart; __syncthreads();
  for (int s = 128; s > 0; s >>= 1) { if (t < s) rbuf[t] += rbuf[t + s]; __syncthreads(); }
  float denom = rbuf[0];
  float val = ((denom > 0.f) ? acc / denom : 0.f) + bo[t];
  if (POOL) {
    val = fmaxf(val, 0.f);
    atomicAdd(&out_pool[(size_t)batch[n] * 256 + t], val);
  } else {
    out_b[(size_t)n * 256 + t] = f2b(val);
  }
}

// ============================================================
// classifier
// ============================================================
__global__ __launch_bounds__(256) void k_final(const float* __restrict__ pooled,
    const float* __restrict__ fw, const float* __restrict__ fb,
    float* __restrict__ out) {
  __shared__ float ps[256];
  __shared__ float ls[NCLS];
  __shared__ float lse_s;
  int g = blockIdx.x, t = threadIdx.x;
  ps[t] = pooled[(size_t)g * 256 + t];
  __syncthreads();
  if (t < NCLS) {
    float a = fb[t];
    for (int k = 0; k < 256; k++) a = fmaf(ps[k], fw[k * NCLS + t], a);
    ls[t] = a;
  }
  __syncthreads();
  if (t == 0) {
    float mxv = ls[0];
    for (int c = 1; c < NCLS; c++) mxv = fmaxf(mxv, ls[c]);
    float se = 0.f;
    for (int c = 0; c < NCLS; c++) se += expf(ls[c] - mxv);
    lse_s = mxv + logf(se);
  }
  __syncthreads();
  if (t < NCLS) out[g * NCLS + t] = ls[t] - lse_s;
}

// ============================================================
extern "C" void kernel_launch(void* const* d_in, const int* in_sizes, int n_in,
                              void* d_out, int out_size, void* d_ws, size_t ws_size,
                              hipStream_t stream) {
  (void)in_sizes; (void)n_in; (void)out_size; (void)ws_size;
  const float* x     = (const float*)d_in[0];
  const int*   ei    = (const int*)d_in[1];
  const int*   src   = ei;
  const int*   dst   = ei + NE;
  const float* raw   = (const float*)d_in[2];
  const int*   batch = (const int*)d_in[3];
  const float* pm_w1 = (const float*)d_in[4];
  const float* pm_b1 = (const float*)d_in[5];
  const float* pm_w2 = (const float*)d_in[6];
  const float* pm_b2 = (const float*)d_in[7];
  const float* pm_ws = (const float*)d_in[8];
  const float* pm_bs = (const float*)d_in[9];
  const float* g1_wl = (const float*)d_in[10];
  const float* g1_bl = (const float*)d_in[11];
  const float* g1_wr = (const float*)d_in[12];
  const float* g1_we = (const float*)d_in[13];
  const float* g1_att= (const float*)d_in[14];
  const float* g1_bo = (const float*)d_in[15];
  const float* g2_wl = (const float*)d_in[16];
  const float* g2_bl = (const float*)d_in[17];
  const float* g2_wr = (const float*)d_in[18];
  const float* g2_we = (const float*)d_in[19];
  const float* g2_att= (const float*)d_in[20];
  const float* g2_bo = (const float*)d_in[21];
  const float* w2    = (const float*)d_in[22];
  const float* b2    = (const float*)d_in[23];
  const float* w3    = (const float*)d_in[24];
  const float* b3    = (const float*)d_in[25];
  const float* w1    = (const float*)d_in[26];
  const float* b1    = (const float*)d_in[27];

  char* wp = (char*)d_ws;
  auto alloc = [&](size_t bytes) -> void* {
    void* p = (void*)wp;
    wp += (bytes + 255) & ~(size_t)255;
    return p;
  };
  // total ~232 MB
  uint8_t* Q    = (uint8_t*)alloc((size_t)NE * 64);            // 102.4 MB
  float*   SCq  = (float*)alloc((size_t)NE * 4);               // 6.4 MB
  unsigned short* NB0 = (unsigned short*)alloc((size_t)N_NODES * 256 * 2); // XL1 -> XL2eff
  unsigned short* NB1 = (unsigned short*)alloc((size_t)N_NODES * 256 * 2); // XR1 -> XR2eff
  unsigned short* NB2 = (unsigned short*)alloc((size_t)N_NODES * 256 * 2); // H
  unsigned short* NB3 = (unsigned short*)alloc((size_t)N_NODES * 256 * 2); // XL2true
  float* LG   = (float*)alloc((size_t)NE * 4);                 // 6.4 MB
  int*   EPOS = (int*)alloc((size_t)NE * 4);                   // 6.4 MB
  int*   SSRC = (int*)alloc((size_t)NE * 4);                   // 6.4 MB
  int*   RP   = (int*)alloc((size_t)(N_NODES + 1) * 4);
  int*   CUR  = (int*)alloc((size_t)N_NODES * 4);
  float* POOL = (float*)alloc((size_t)NGR * 256 * 4);
  float* Mm   = (float*)alloc((size_t)64 * 256 * 4);
  float* Wa   = (float*)alloc((size_t)64 * 256 * 4);
  float* Ths  = (float*)alloc((size_t)256 * 256 * 4);
  float* Thd  = (float*)alloc((size_t)256 * 256 * 4);
  float* B2V  = (float*)alloc((size_t)256 * 4);

  hipMemsetAsync(CUR, 0, (size_t)N_NODES * 4, stream);
  hipMemsetAsync(POOL, 0, (size_t)NGR * 256 * 4, stream);

  // CSR by dst (shared by both convs)
  k_count  <<<NE / 256, 256, 0, stream>>>(dst, CUR);
  k_scan   <<<1, 1024, 0, stream>>>(CUR, RP);
  k_scatter<<<NE / 256, 256, 0, stream>>>(src, dst, CUR, SSRC, EPOS);

  // folded conv2 matrices
  k_pre1<<<128, 256, 0, stream>>>(w3, g2_we, Mm, Wa);
  k_pre2<<<513, 256, 0, stream>>>(w2, b2, b3, Mm, g2_we, Ths, Thd, B2V);

  // edge_attr (quantized)
  k_perm<<<NE / 256, 256, 0, stream>>>(raw, pm_w1, pm_b1, pm_w2, pm_b2, pm_ws, pm_bs, Q, SCq);

  dim3 gg((N_NODES + 63) / 64, 4);
  // conv1
  k_gemm_x<true ><<<gg, 256, 0, stream>>>(x, g1_wl, g1_bl, NB0, N_NODES);   // XL1
  k_gemm_x<false><<<gg, 256, 0, stream>>>(x, g1_wr, nullptr, NB1, N_NODES); // XR1
  k_elogit<false><<<NE / 64, 256, 0, stream>>>(Q, SCq, src, dst, EPOS, NB0, NB1,
                                               g1_we, g1_att, nullptr, LG);
  k_agg<false><<<N_NODES, 256, 0, stream>>>(RP, SSRC, LG, NB0, g1_bo, batch, NB2, nullptr); // H

  // conv2 node features (k_msg folded away algebraically)
  k_gemm_h<false, true ><<<gg, 256, 0, stream>>>(NB2, g2_wl, nullptr, g2_bl, NB3, N_NODES); // XL2true
  k_gemm_h<true,  true ><<<gg, 256, 0, stream>>>(NB2, g2_wl, Ths, g2_bl, NB0, N_NODES);     // XL2eff
  k_gemm_h<true,  false><<<gg, 256, 0, stream>>>(NB2, g2_wr, Thd, nullptr, NB1, N_NODES);   // XR2eff

  // conv2
  k_elogit<true><<<NE / 64, 256, 0, stream>>>(Q, SCq, src, dst, EPOS, NB0, NB1,
                                              Wa, g2_att, B2V, LG);
  k_agg<true><<<N_NODES, 256, 0, stream>>>(RP, SSRC, LG, NB3, g2_bo, batch, nullptr, POOL);

  // classifier
  k_final<<<NGR, 256, 0, stream>>>(POOL, w1, b1, (float*)d_out);
}

// Round 8
// 3405.182 us; speedup vs baseline: 1.3256x; 1.3256x over previous
//
#include <hip/hip_runtime.h>
#include <cstdint>
#include <cstddef>

#define N_NODES 50000
#define NE      1600000
#define FIN     128
#define HDIM    256
#define EDIM    64
#define NGR     64
#define NCLS    10

using short8 = __attribute__((ext_vector_type(8))) short;
using f32x4  = __attribute__((ext_vector_type(4))) float;

// ---------- bf16 helpers (raw ushort storage, fp32 compute) ----------
__device__ __forceinline__ float b2f(unsigned short u) {
  union { uint32_t i; float f; } v; v.i = ((uint32_t)u) << 16; return v.f;
}
__device__ __forceinline__ unsigned short f2b(float f) {
  union { float f; uint32_t i; } v; v.f = f;
  uint32_t r = v.i + 0x7fff + ((v.i >> 16) & 1);   // round-to-nearest-even
  return (unsigned short)(r >> 16);
}

// ============================================================
// CSR build (by dst)
// ============================================================
__global__ void k_count(const int* __restrict__ dst, int* __restrict__ cnt) {
  int e = blockIdx.x * 256 + threadIdx.x;
  if (e < NE) atomicAdd(&cnt[dst[e]], 1);
}

__global__ __launch_bounds__(1024) void k_scan(int* __restrict__ cnt, int* __restrict__ rp) {
  __shared__ int s[1024];
  __shared__ int base_s;
  int t = threadIdx.x;
  if (t == 0) { base_s = 0; rp[0] = 0; }
  __syncthreads();
  for (int c0 = 0; c0 < N_NODES; c0 += 1024) {
    int i = c0 + t;
    int v = (i < N_NODES) ? cnt[i] : 0;
    s[t] = v;
    __syncthreads();
    for (int off = 1; off < 1024; off <<= 1) {
      int add = (t >= off) ? s[t - off] : 0;
      __syncthreads();
      s[t] += add;
      __syncthreads();
    }
    int incl = s[t];
    int base = base_s;
    if (i < N_NODES) {
      int excl = base + incl - v;
      cnt[i] = excl;     // becomes scatter cursor
      rp[i]  = excl;
      if (i == N_NODES - 1) rp[N_NODES] = base + incl;
    }
    __syncthreads();
    if (t == 1023) base_s = base + incl;
    __syncthreads();
  }
}

__global__ void k_scatter(const int* __restrict__ src, const int* __restrict__ dst,
                          int* __restrict__ cur, int* __restrict__ ssrc,
                          int* __restrict__ epos) {
  int e = blockIdx.x * 256 + threadIdx.x;
  if (e < NE) {
    int d = dst[e];
    int pos = atomicAdd(&cur[d], 1);
    ssrc[pos] = src[e];
    epos[e] = pos;
  }
}

// ============================================================
// precompute folded conv2 matrices:
//  M    = w3b @ g2_we        (64x256)   [w3b = w3 rows 64..127]
//  W_a  = w3a @ g2_we        (64x256)   [w3a = w3 rows 0..63]
// ============================================================
__global__ __launch_bounds__(256) void k_pre1(const float* __restrict__ w3,
    const float* __restrict__ g2we, float* __restrict__ M, float* __restrict__ Wa) {
  int idx = blockIdx.x * 256 + threadIdx.x;          // 32768
  int which = idx >> 14;                              // 0: M (w3b), 1: Wa (w3a)
  int k = (idx >> 8) & 63, d = idx & 255;
  const float* wrow = w3 + (size_t)(which ? k : (64 + k)) * 64;
  float a = 0.f;
#pragma unroll 8
  for (int j = 0; j < 64; j++) a = fmaf(wrow[j], g2we[j * 256 + d], a);
  (which ? Wa : M)[k * 256 + d] = a;
}

// ============================================================
//  T_hs = w2[0:256]   @ M    (256x256)
//  T_hd = w2[256:512] @ M    (256x256)
//  bias2 = b2 @ M + b3 @ g2_we   (256)
// ============================================================
__global__ __launch_bounds__(256) void k_pre2(const float* __restrict__ w2,
    const float* __restrict__ b2, const float* __restrict__ b3,
    const float* __restrict__ M, const float* __restrict__ g2we,
    float* __restrict__ Ths, float* __restrict__ Thd, float* __restrict__ bias2) {
  int idx = blockIdx.x * 256 + threadIdx.x;          // grid 513 -> 131328
  if (idx < 65536) {
    int k = idx >> 8, d = idx & 255;
    float a = 0.f;
#pragma unroll 8
    for (int j = 0; j < 64; j++) a = fmaf(w2[(size_t)k * 64 + j], M[j * 256 + d], a);
    Ths[(size_t)k * 256 + d] = a;
  } else if (idx < 131072) {
    int k = (idx - 65536) >> 8, d = idx & 255;
    float a = 0.f;
#pragma unroll 8
    for (int j = 0; j < 64; j++) a = fmaf(w2[(size_t)(256 + k) * 64 + j], M[j * 256 + d], a);
    Thd[(size_t)k * 256 + d] = a;
  } else if (idx < 131328) {
    int d = idx - 131072;
    float a = 0.f;
#pragma unroll 8
    for (int j = 0; j < 64; j++) {
      a = fmaf(b2[j], M[j * 256 + d], a);
      a = fmaf(b3[j], g2we[j * 256 + d], a);
    }
    bias2[d] = a;
  }
}

// ============================================================
// transpose + bf16-convert edge-weight matrix: W[64][256] -> WT[256][64]
// ============================================================
__global__ __launch_bounds__(256) void k_prew(const float* __restrict__ W,
                                              unsigned short* __restrict__ WT) {
  int idx = blockIdx.x * 256 + threadIdx.x;  // 16384
  int n = idx >> 6, k = idx & 63;
  WT[idx] = f2b(W[k * 256 + n]);
}

// ============================================================
// perm_invariant_net per-edge; output quantized uint8 with per-edge scale
// ============================================================
__global__ __launch_bounds__(256) void k_perm(const float* __restrict__ raw,
    const float* __restrict__ pw1, const float* __restrict__ pb1,
    const float* __restrict__ pw2, const float* __restrict__ pb2,
    const float* __restrict__ pws, const float* __restrict__ pbs,
    uint8_t* __restrict__ Q, float* __restrict__ SC) {
  int e = blockIdx.x * 256 + threadIdx.x;   // NE % 256 == 0
  const float4* rp4 = reinterpret_cast<const float4*>(raw + (size_t)e * 8);
  float4 v0 = rp4[0], v1 = rp4[1];
  float x0 = v0.x, x1 = v0.y, x2 = v0.z, x3 = v0.w;
  float x4 = v1.x, x5 = v1.y, x6 = v1.z, x7 = v1.w;
#define CE(a,b) { float lo_ = fminf(a,b), hi_ = fmaxf(a,b); a = lo_; b = hi_; }
  CE(x0,x1) CE(x2,x3) CE(x4,x5) CE(x6,x7)
  CE(x0,x2) CE(x1,x3) CE(x4,x6) CE(x5,x7)
  CE(x1,x2) CE(x5,x6) CE(x0,x4) CE(x3,x7)
  CE(x1,x5) CE(x2,x6)
  CE(x1,x4) CE(x3,x6)
  CE(x2,x4) CE(x3,x5)
  CE(x3,x4)
#undef CE
  float xs[8] = {x0,x1,x2,x3,x4,x5,x6,x7};
  float sum = x0+x1+x2+x3+x4+x5+x6+x7;
  float mean = sum * 0.125f;
  float var = 0.f;
#pragma unroll
  for (int i = 0; i < 8; i++) { float d = xs[i] - mean; var = fmaf(d, d, var); }
  float sd  = sqrtf(var * (1.f / 7.f));   // ddof=1
  float rng = x7 - x0;
  float mx  = x7;

  float f[64];
#pragma unroll
  for (int o = 0; o < 64; o++) f[o] = pb2[o];
#pragma unroll 2
  for (int j = 0; j < 256; j++) {
    float h = pb1[j];
#pragma unroll
    for (int i = 0; i < 8; i++) h = fmaf(xs[i], pw1[i * 256 + j], h);
    h = fmaxf(h, 0.f);
#pragma unroll
    for (int o = 0; o < 64; o++) f[o] = fmaf(h, pw2[j * 64 + o], f[o]);
  }
  float g[64];
#pragma unroll
  for (int o = 0; o < 64; o++)
    g[o] = pbs[o] + rng * pws[64 * 64 + o] + sd * pws[65 * 64 + o] + mx * pws[66 * 64 + o];
#pragma unroll
  for (int k = 0; k < 64; k++) {
    float fk = f[k];
#pragma unroll
    for (int o = 0; o < 64; o++) g[o] = fmaf(fk, pws[k * 64 + o], g[o]);
  }
  // relu + row max
  float mrow = 0.f;
#pragma unroll
  for (int o = 0; o < 64; o++) { g[o] = fmaxf(g[o], 0.f); mrow = fmaxf(mrow, g[o]); }
  float inv = (mrow > 0.f) ? (255.f / mrow) : 0.f;
  SC[e] = mrow * (1.f / 255.f);
  uint32_t pk[16];
#pragma unroll
  for (int w = 0; w < 16; w++) {
    uint32_t q0 = (uint32_t)(g[4*w+0] * inv + 0.5f);
    uint32_t q1 = (uint32_t)(g[4*w+1] * inv + 0.5f);
    uint32_t q2 = (uint32_t)(g[4*w+2] * inv + 0.5f);
    uint32_t q3 = (uint32_t)(g[4*w+3] * inv + 0.5f);
    pk[w] = q0 | (q1 << 8) | (q2 << 16) | (q3 << 24);
  }
  uint4* qp = reinterpret_cast<uint4*>(Q + (size_t)e * 64);
#pragma unroll
  for (int w = 0; w < 4; w++) {
    uint4 v; v.x = pk[4*w]; v.y = pk[4*w+1]; v.z = pk[4*w+2]; v.w = pk[4*w+3];
    qp[w] = v;
  }
}

// ============================================================
// conv1 node GEMM: out_bf16[M][256] = x_f32 @ W (+bias), K=128
// ============================================================
template<bool BIAS>
__global__ __launch_bounds__(256) void k_gemm_x(const float* __restrict__ A,
    const float* __restrict__ W, const float* __restrict__ bias,
    unsigned short* __restrict__ out, int Mrows) {
  __shared__ float As[32][68];
  __shared__ float Bs[32][64];
  int t = threadIdx.x;
  int m0 = blockIdx.x * 64, n0 = blockIdx.y * 64;
  int tm = t & 15, tn = t >> 4;
  float acc[4][4] = {};
  for (int k0 = 0; k0 < FIN; k0 += 32) {
    {
      int e = t >> 2, kk = (t & 3) * 8;
      int gm = m0 + e;
      float va[8];
      if (gm < Mrows) {
        const float* ap = A + (size_t)gm * FIN + k0 + kk;
        float4 a0 = *reinterpret_cast<const float4*>(ap);
        float4 a1 = *reinterpret_cast<const float4*>(ap + 4);
        va[0]=a0.x; va[1]=a0.y; va[2]=a0.z; va[3]=a0.w;
        va[4]=a1.x; va[5]=a1.y; va[6]=a1.z; va[7]=a1.w;
      } else {
#pragma unroll
        for (int q = 0; q < 8; q++) va[q] = 0.f;
      }
#pragma unroll
      for (int q = 0; q < 8; q++) As[kk + q][e] = va[q];
    }
    {
      int r = t >> 3, c = (t & 7) * 8;
      const float* wp = W + (size_t)(k0 + r) * 256 + n0 + c;
      *reinterpret_cast<float4*>(&Bs[r][c])     = *reinterpret_cast<const float4*>(wp);
      *reinterpret_cast<float4*>(&Bs[r][c + 4]) = *reinterpret_cast<const float4*>(wp + 4);
    }
    __syncthreads();
#pragma unroll
    for (int k = 0; k < 32; k++) {
      float4 a4 = *reinterpret_cast<const float4*>(&As[k][tm * 4]);
      float4 b4 = *reinterpret_cast<const float4*>(&Bs[k][tn * 4]);
      float av[4] = {a4.x, a4.y, a4.z, a4.w};
      float bv[4] = {b4.x, b4.y, b4.z, b4.w};
#pragma unroll
      for (int i = 0; i < 4; i++)
#pragma unroll
        for (int j = 0; j < 4; j++)
          acc[i][j] = fmaf(av[i], bv[j], acc[i][j]);
    }
    __syncthreads();
  }
  float bv4[4] = {0.f, 0.f, 0.f, 0.f};
  if (BIAS) {
#pragma unroll
    for (int j = 0; j < 4; j++) bv4[j] = bias[n0 + tn * 4 + j];
  }
#pragma unroll
  for (int i = 0; i < 4; i++) {
    int gm = m0 + tm * 4 + i;
    if (gm < Mrows) {
      ushort4 o;
      o.x = f2b(acc[i][0] + bv4[0]); o.y = f2b(acc[i][1] + bv4[1]);
      o.z = f2b(acc[i][2] + bv4[2]); o.w = f2b(acc[i][3] + bv4[3]);
      *reinterpret_cast<ushort4*>(out + (size_t)gm * 256 + n0 + tn * 4) = o;
    }
  }
}

// ============================================================
// conv2 node GEMMs from bf16 H:
//   out = relu(h) @ W1  [+ h @ W2]  [+ bias]    (K=256 per pass)
// ============================================================
template<bool W2P, bool BIAS>
__global__ __launch_bounds__(256) void k_gemm_h(const unsigned short* __restrict__ H,
    const float* __restrict__ W1, const float* __restrict__ W2,
    const float* __restrict__ bias, unsigned short* __restrict__ out, int Mrows) {
  __shared__ float As[32][68];
  __shared__ float Bs[32][64];
  int t = threadIdx.x;
  int m0 = blockIdx.x * 64, n0 = blockIdx.y * 64;
  int tm = t & 15, tn = t >> 4;
  float acc[4][4] = {};
  const int passes = W2P ? 2 : 1;
  for (int ps = 0; ps < passes; ps++) {
    const float* W = ps ? W2 : W1;
    for (int k0 = 0; k0 < HDIM; k0 += 32) {
      {
        int e = t >> 2, kk = (t & 3) * 8;
        int gm = m0 + e;
        float va[8];
        if (gm < Mrows) {
          uint4 hv = *reinterpret_cast<const uint4*>(H + (size_t)gm * 256 + k0 + kk);
          uint32_t wd[4] = {hv.x, hv.y, hv.z, hv.w};
#pragma unroll
          for (int q = 0; q < 4; q++) {
            va[2*q]   = b2f((unsigned short)(wd[q] & 0xffff));
            va[2*q+1] = b2f((unsigned short)(wd[q] >> 16));
          }
        } else {
#pragma unroll
          for (int q = 0; q < 8; q++) va[q] = 0.f;
        }
#pragma unroll
        for (int q = 0; q < 8; q++) {
          float v = va[q];
          if (ps == 0) v = fmaxf(v, 0.f);   // relu pass
          As[kk + q][e] = v;
        }
      }
      {
        int r = t >> 3, c = (t & 7) * 8;
        const float* wp = W + (size_t)(k0 + r) * 256 + n0 + c;
        *reinterpret_cast<float4*>(&Bs[r][c])     = *reinterpret_cast<const float4*>(wp);
        *reinterpret_cast<float4*>(&Bs[r][c + 4]) = *reinterpret_cast<const float4*>(wp + 4);
      }
      __syncthreads();
#pragma unroll
      for (int k = 0; k < 32; k++) {
        float4 a4 = *reinterpret_cast<const float4*>(&As[k][tm * 4]);
        float4 b4 = *reinterpret_cast<const float4*>(&Bs[k][tn * 4]);
        float av[4] = {a4.x, a4.y, a4.z, a4.w};
        float bv[4] = {b4.x, b4.y, b4.z, b4.w};
#pragma unroll
        for (int i = 0; i < 4; i++)
#pragma unroll
          for (int j = 0; j < 4; j++)
            acc[i][j] = fmaf(av[i], bv[j], acc[i][j]);
      }
      __syncthreads();
    }
  }
  float bv4[4] = {0.f, 0.f, 0.f, 0.f};
  if (BIAS) {
#pragma unroll
    for (int j = 0; j < 4; j++) bv4[j] = bias[n0 + tn * 4 + j];
  }
#pragma unroll
  for (int i = 0; i < 4; i++) {
    int gm = m0 + tm * 4 + i;
    if (gm < Mrows) {
      ushort4 o;
      o.x = f2b(acc[i][0] + bv4[0]); o.y = f2b(acc[i][1] + bv4[1]);
      o.z = f2b(acc[i][2] + bv4[2]); o.w = f2b(acc[i][3] + bv4[3]);
      *reinterpret_cast<ushort4*>(out + (size_t)gm * 256 + n0 + tn * 4) = o;
    }
  }
}

// ============================================================
// attention logits, MFMA version.
// Per block: 64 edges. 4 waves; wave w owns edges [w*16, w*16+16).
// GEMM: E (16x64, dequant uint8->bf16, direct global->reg) @ weT (bf16 [256][64])
// mfma_f32_16x16x32_bf16: A lane: row=l&15, k=(l>>4)*8+i ; B lane: col=l&15, same k.
// C/D: col=lane&15, row=(lane>>4)*4+reg (verified layout).
// Epilogue: s = acc + xl[src] + xr[dst] (+ebias); leaky; dot att;
//           shfl_xor reduce over the 16-lane col group; scatter to CSR slot.
// ============================================================
template<bool EBIAS>
__global__ __launch_bounds__(256) void k_elogit(
    const uint8_t* __restrict__ Q, const float* __restrict__ SC,
    const int* __restrict__ src, const int* __restrict__ dst,
    const int* __restrict__ epos,
    const unsigned short* __restrict__ xl, const unsigned short* __restrict__ xr,
    const unsigned short* __restrict__ WT, const float* __restrict__ att,
    const float* __restrict__ ebias, float* __restrict__ lg) {
  __shared__ int   s_src[64], s_dst[64], s_pos[64];
  __shared__ float att_s[256];
  __shared__ float eb_s[256];
  int t = threadIdx.x;
  int e0 = blockIdx.x * 64;                 // NE % 64 == 0
  if (t < 64) { s_src[t] = src[e0 + t]; s_dst[t] = dst[e0 + t]; s_pos[t] = epos[e0 + t]; }
  att_s[t] = att[t];
  if (EBIAS) eb_s[t] = ebias[t];
  __syncthreads();

  int w = t >> 6, l = t & 63;
  int la = l & 15, kg = l >> 4;             // col-lane / k-group
  int ebase = w * 16;                       // edge offset within block

  // ---- A fragments: dequant Q rows straight into registers ----
  const uint8_t* qrow = Q + (size_t)(e0 + ebase + la) * 64 + kg * 8;
  uint2 qa = *reinterpret_cast<const uint2*>(qrow);        // k 0..31 slice
  uint2 qb = *reinterpret_cast<const uint2*>(qrow + 32);   // k 32..63 slice
  float sc = SC[e0 + ebase + la];
  short8 a0, a1;
#pragma unroll
  for (int j = 0; j < 4; j++) {
    a0[j]     = (short)f2b((float)((qa.x >> (8 * j)) & 0xff) * sc);
    a0[4 + j] = (short)f2b((float)((qa.y >> (8 * j)) & 0xff) * sc);
    a1[j]     = (short)f2b((float)((qb.x >> (8 * j)) & 0xff) * sc);
    a1[4 + j] = (short)f2b((float)((qb.y >> (8 * j)) & 0xff) * sc);
  }

  // ---- MFMA over 16 N-tiles ----
  f32x4 acc[16];
#pragma unroll
  for (int nt = 0; nt < 16; nt++) acc[nt] = (f32x4){0.f, 0.f, 0.f, 0.f};
#pragma unroll
  for (int nt = 0; nt < 16; nt++) {
    const unsigned short* wtp = WT + (size_t)(nt * 16 + la) * 64 + kg * 8;
    short8 b0 = *reinterpret_cast<const short8*>(wtp);
    short8 b1 = *reinterpret_cast<const short8*>(wtp + 32);
    acc[nt] = __builtin_amdgcn_mfma_f32_16x16x32_bf16(a0, b0, acc[nt], 0, 0, 0);
    acc[nt] = __builtin_amdgcn_mfma_f32_16x16x32_bf16(a1, b1, acc[nt], 0, 0, 0);
  }

  // ---- epilogue ----
  float p[4] = {0.f, 0.f, 0.f, 0.f};
#pragma unroll
  for (int nt = 0; nt < 16; nt++) {
    int n = nt * 16 + la;
    float attn = att_s[n];
    float ebn = EBIAS ? eb_s[n] : 0.f;
#pragma unroll
    for (int r = 0; r < 4; r++) {
      int e = ebase + kg * 4 + r;           // edge within block (D row)
      float xlv = b2f(xl[(size_t)s_src[e] * 256 + n]);
      float xrv = b2f(xr[(size_t)s_dst[e] * 256 + n]);
      float sv = acc[nt][r] + xlv + xrv + ebn;
      sv = (sv > 0.f) ? sv : 0.2f * sv;
      p[r] = fmaf(sv, attn, p[r]);
    }
  }
  // reduce over the 16 col-lanes (la bits 0..3)
#pragma unroll
  for (int r = 0; r < 4; r++) {
    float v = p[r];
    v += __shfl_xor(v, 1);
    v += __shfl_xor(v, 2);
    v += __shfl_xor(v, 4);
    v += __shfl_xor(v, 8);
    p[r] = v;
  }
  if (la == 0) {
#pragma unroll
    for (int r = 0; r < 4; r++) {
      int e = ebase + kg * 4 + r;
      lg[s_pos[e]] = p[r];                  // scattered into CSR order
    }
  }
}

// ============================================================
// softmax-aggregation per dst node (CSR, sequential reads)
// ============================================================
template<bool POOL>
__global__ __launch_bounds__(256) void k_agg(const int* __restrict__ rp,
    const int* __restrict__ ssrc, const float* __restrict__ lg,
    const unsigned short* __restrict__ xl, const float* __restrict__ bo,
    const int* __restrict__ batch,
    unsigned short* __restrict__ out_b, float* __restrict__ out_pool) {
  int n = blockIdx.x, t = threadIdx.x;
  int beg = rp[n], deg = rp[n + 1] - beg;
  __shared__ float ws_[256];
  __shared__ int   ss_[256];
  __shared__ float rbuf[256];
  float lm = -3.4e38f;
  for (int i = t; i < deg; i += 256) lm = fmaxf(lm, lg[beg + i]);
  rbuf[t] = lm; __syncthreads();
  for (int s = 128; s > 0; s >>= 1) { if (t < s) rbuf[t] = fmaxf(rbuf[t], rbuf[t + s]); __syncthreads(); }
  float m = rbuf[0];
  __syncthreads();
  float acc = 0.f, dpart = 0.f;
  for (int c0 = 0; c0 < deg; c0 += 256) {
    int i = c0 + t;
    float w = 0.f; int sidx = 0;
    if (i < deg) { w = expf(lg[beg + i] - m); sidx = ssrc[beg + i]; dpart += w; }
    ws_[t] = w; ss_[t] = sidx;
    __syncthreads();
    int lim = min(256, deg - c0);
    for (int j = 0; j < lim; j++)
      acc = fmaf(ws_[j], b2f(xl[(size_t)ss_[j] * 256 + t]), acc);
    __syncthreads();
  }
  rbuf[t] = dpart; __syncthreads();
  for (int s = 128; s > 0; s >>= 1) { if (t < s) rbuf[t] += rbuf[t + s]; __syncthreads(); }
  float denom = rbuf[0];
  float val = ((denom > 0.f) ? acc / denom : 0.f) + bo[t];
  if (POOL) {
    val = fmaxf(val, 0.f);
    atomicAdd(&out_pool[(size_t)batch[n] * 256 + t], val);
  } else {
    out_b[(size_t)n * 256 + t] = f2b(val);
  }
}

// ============================================================
// classifier
// ============================================================
__global__ __launch_bounds__(256) void k_final(const float* __restrict__ pooled,
    const float* __restrict__ fw, const float* __restrict__ fb,
    float* __restrict__ out) {
  __shared__ float ps[256];
  __shared__ float ls[NCLS];
  __shared__ float lse_s;
  int g = blockIdx.x, t = threadIdx.x;
  ps[t] = pooled[(size_t)g * 256 + t];
  __syncthreads();
  if (t < NCLS) {
    float a = fb[t];
    for (int k = 0; k < 256; k++) a = fmaf(ps[k], fw[k * NCLS + t], a);
    ls[t] = a;
  }
  __syncthreads();
  if (t == 0) {
    float mxv = ls[0];
    for (int c = 1; c < NCLS; c++) mxv = fmaxf(mxv, ls[c]);
    float se = 0.f;
    for (int c = 0; c < NCLS; c++) se += expf(ls[c] - mxv);
    lse_s = mxv + logf(se);
  }
  __syncthreads();
  if (t < NCLS) out[g * NCLS + t] = ls[t] - lse_s;
}

// ============================================================
extern "C" void kernel_launch(void* const* d_in, const int* in_sizes, int n_in,
                              void* d_out, int out_size, void* d_ws, size_t ws_size,
                              hipStream_t stream) {
  (void)in_sizes; (void)n_in; (void)out_size; (void)ws_size;
  const float* x     = (const float*)d_in[0];
  const int*   ei    = (const int*)d_in[1];
  const int*   src   = ei;
  const int*   dst   = ei + NE;
  const float* raw   = (const float*)d_in[2];
  const int*   batch = (const int*)d_in[3];
  const float* pm_w1 = (const float*)d_in[4];
  const float* pm_b1 = (const float*)d_in[5];
  const float* pm_w2 = (const float*)d_in[6];
  const float* pm_b2 = (const float*)d_in[7];
  const float* pm_ws = (const float*)d_in[8];
  const float* pm_bs = (const float*)d_in[9];
  const float* g1_wl = (const float*)d_in[10];
  const float* g1_bl = (const float*)d_in[11];
  const float* g1_wr = (const float*)d_in[12];
  const float* g1_we = (const float*)d_in[13];
  const float* g1_att= (const float*)d_in[14];
  const float* g1_bo = (const float*)d_in[15];
  const float* g2_wl = (const float*)d_in[16];
  const float* g2_bl = (const float*)d_in[17];
  const float* g2_wr = (const float*)d_in[18];
  const float* g2_we = (const float*)d_in[19];
  const float* g2_att= (const float*)d_in[20];
  const float* g2_bo = (const float*)d_in[21];
  const float* w2    = (const float*)d_in[22];
  const float* b2    = (const float*)d_in[23];
  const float* w3    = (const float*)d_in[24];
  const float* b3    = (const float*)d_in[25];
  const float* w1    = (const float*)d_in[26];
  const float* b1    = (const float*)d_in[27];

  char* wp = (char*)d_ws;
  auto alloc = [&](size_t bytes) -> void* {
    void* p = (void*)wp;
    wp += (bytes + 255) & ~(size_t)255;
    return p;
  };
  // total ~232 MB
  uint8_t* Q    = (uint8_t*)alloc((size_t)NE * 64);            // 102.4 MB
  float*   SCq  = (float*)alloc((size_t)NE * 4);               // 6.4 MB
  unsigned short* NB0 = (unsigned short*)alloc((size_t)N_NODES * 256 * 2); // XL1 -> XL2eff
  unsigned short* NB1 = (unsigned short*)alloc((size_t)N_NODES * 256 * 2); // XR1 -> XR2eff
  unsigned short* NB2 = (unsigned short*)alloc((size_t)N_NODES * 256 * 2); // H
  unsigned short* NB3 = (unsigned short*)alloc((size_t)N_NODES * 256 * 2); // XL2true
  float* LG   = (float*)alloc((size_t)NE * 4);                 // 6.4 MB
  int*   EPOS = (int*)alloc((size_t)NE * 4);                   // 6.4 MB
  int*   SSRC = (int*)alloc((size_t)NE * 4);                   // 6.4 MB
  int*   RP   = (int*)alloc((size_t)(N_NODES + 1) * 4);
  int*   CUR  = (int*)alloc((size_t)N_NODES * 4);
  float* POOL = (float*)alloc((size_t)NGR * 256 * 4);
  float* Mm   = (float*)alloc((size_t)64 * 256 * 4);
  float* Wa   = (float*)alloc((size_t)64 * 256 * 4);
  float* Ths  = (float*)alloc((size_t)256 * 256 * 4);
  float* Thd  = (float*)alloc((size_t)256 * 256 * 4);
  float* B2V  = (float*)alloc((size_t)256 * 4);
  unsigned short* WT1 = (unsigned short*)alloc((size_t)256 * 64 * 2);  // g1_we^T bf16
  unsigned short* WT2 = (unsigned short*)alloc((size_t)256 * 64 * 2);  // Wa^T bf16

  hipMemsetAsync(CUR, 0, (size_t)N_NODES * 4, stream);
  hipMemsetAsync(POOL, 0, (size_t)NGR * 256 * 4, stream);

  // CSR by dst (shared by both convs)
  k_count  <<<NE / 256, 256, 0, stream>>>(dst, CUR);
  k_scan   <<<1, 1024, 0, stream>>>(CUR, RP);
  k_scatter<<<NE / 256, 256, 0, stream>>>(src, dst, CUR, SSRC, EPOS);

  // folded conv2 matrices + transposed bf16 edge-weight tables
  k_pre1<<<128, 256, 0, stream>>>(w3, g2_we, Mm, Wa);
  k_pre2<<<513, 256, 0, stream>>>(w2, b2, b3, Mm, g2_we, Ths, Thd, B2V);
  k_prew<<<64, 256, 0, stream>>>(g1_we, WT1);
  k_prew<<<64, 256, 0, stream>>>(Wa, WT2);

  // edge_attr (quantized)
  k_perm<<<NE / 256, 256, 0, stream>>>(raw, pm_w1, pm_b1, pm_w2, pm_b2, pm_ws, pm_bs, Q, SCq);

  dim3 gg((N_NODES + 63) / 64, 4);
  // conv1
  k_gemm_x<true ><<<gg, 256, 0, stream>>>(x, g1_wl, g1_bl, NB0, N_NODES);   // XL1
  k_gemm_x<false><<<gg, 256, 0, stream>>>(x, g1_wr, nullptr, NB1, N_NODES); // XR1
  k_elogit<false><<<NE / 64, 256, 0, stream>>>(Q, SCq, src, dst, EPOS, NB0, NB1,
                                               WT1, g1_att, nullptr, LG);
  k_agg<false><<<N_NODES, 256, 0, stream>>>(RP, SSRC, LG, NB0, g1_bo, batch, NB2, nullptr); // H

  // conv2 node features (k_msg folded away algebraically)
  k_gemm_h<false, true ><<<gg, 256, 0, stream>>>(NB2, g2_wl, nullptr, g2_bl, NB3, N_NODES); // XL2true
  k_gemm_h<true,  true ><<<gg, 256, 0, stream>>>(NB2, g2_wl, Ths, g2_bl, NB0, N_NODES);     // XL2eff
  k_gemm_h<true,  false><<<gg, 256, 0, stream>>>(NB2, g2_wr, Thd, nullptr, NB1, N_NODES);   // XR2eff

  // conv2
  k_elogit<true><<<NE / 64, 256, 0, stream>>>(Q, SCq, src, dst, EPOS, NB0, NB1,
                                              WT2, g2_att, B2V, LG);
  k_agg<true><<<N_NODES, 256, 0, stream>>>(RP, SSRC, LG, NB3, g2_bo, batch, nullptr, POOL);

  // classifier
  k_final<<<NGR, 256, 0, stream>>>(POOL, w1, b1, (float*)d_out);
}